// Round 2
// baseline (163.034 us; speedup 1.0000x reference)
//
#include <hip/hip_runtime.h>
#include <math.h>

// Problem constants
#define NZ 4
#define NN 256
#define NC 32
#define NH 100
#define GAMMA 0.3f   // 1/spacing = NUM_BASIS/MAX_RADIUS = 3/10

// ---------------------------------------------------------------------------
// K1: W[z,b,h,i] = sum_j rw2[h, i*32+j] * x[z,b,j]
// grid: 256 blocks = z(4) x bgrp(64), 4 b's per block; 256 threads
// ---------------------------------------------------------------------------
__global__ __launch_bounds__(256) void k1_W(const float* __restrict__ x,
                                            const float* __restrict__ rw2,
                                            float* __restrict__ W) {
    int bid = blockIdx.x;
    int z = bid >> 6, bgrp = bid & 63;
    int b0 = bgrp * 4;
    int t = threadIdx.x;
    __shared__ float xs[4][32];
    if (t < 128) {
        int q = t >> 5, j = t & 31;
        xs[q][j] = x[(z * 256 + b0 + q) * 32 + j];
    }
    __syncthreads();
    for (int e = t; e < 3200; e += 256) {
        int h = e >> 5, i = e & 31;
        const float4* w4 = (const float4*)(rw2 + h * 1024 + i * 32);
        float a0 = 0.f, a1 = 0.f, a2 = 0.f, a3 = 0.f;
        #pragma unroll
        for (int j4 = 0; j4 < 8; ++j4) {
            float4 wv = w4[j4];
            int j = j4 * 4;
            a0 += wv.x * xs[0][j] + wv.y * xs[0][j + 1] + wv.z * xs[0][j + 2] + wv.w * xs[0][j + 3];
            a1 += wv.x * xs[1][j] + wv.y * xs[1][j + 1] + wv.z * xs[1][j + 2] + wv.w * xs[1][j + 3];
            a2 += wv.x * xs[2][j] + wv.y * xs[2][j + 1] + wv.z * xs[2][j + 2] + wv.w * xs[2][j + 3];
            a3 += wv.x * xs[3][j] + wv.y * xs[3][j + 1] + wv.z * xs[3][j + 2] + wv.w * xs[3][j + 3];
        }
        W[((z * 256 + b0 + 0) * 100 + h) * 32 + i] = a0;
        W[((z * 256 + b0 + 1) * 100 + h) * 32 + i] = a1;
        W[((z * 256 + b0 + 2) * 100 + h) * 32 + i] = a2;
        W[((z * 256 + b0 + 3) * 100 + h) * 32 + i] = a3;
    }
}

// ---------------------------------------------------------------------------
// K2: part[z,bc,a,i] = sum_{b in chunk} sum_h hid(z,a,b,h) * W[z,b,h,i]
// grid: 256 blocks = z(4) x bc(64), b-chunk of 4; 256 threads
// hid computed on the fly; a processed in halves of 128 (LDS budget)
// thread tile: 4a x 4i registers
// ---------------------------------------------------------------------------
__global__ __launch_bounds__(256) void k2_main(const float* __restrict__ xyz,
                                               const float* __restrict__ rw1,
                                               const float* __restrict__ W,
                                               float* __restrict__ part) {
    int bid = blockIdx.x;
    int z = bid >> 6, bc = bid & 63;
    int b0 = bc * 4;
    int t = threadIdx.x;
    int a_grp = t >> 3;   // 0..31
    int i_grp = t & 7;    // 0..7

    __shared__ __align__(16) float hid[100 * 128];  // [h][a-within-half]
    __shared__ float bas[3][128];
    __shared__ float rw1s[304];
    for (int e = t; e < 300; e += 256) rw1s[e] = rw1[e];   // rw1 is [3][100] flat — FIXED: grid-stride

    float acc[2][4][4];
    #pragma unroll
    for (int hf = 0; hf < 2; ++hf)
        #pragma unroll
        for (int ai = 0; ai < 4; ++ai)
            #pragma unroll
            for (int ij = 0; ij < 4; ++ij) acc[hf][ai][ij] = 0.f;

    for (int bi = 0; bi < 4; ++bi) {
        int b = b0 + bi;
        float bx = xyz[(z * 256 + b) * 3 + 0];
        float by = xyz[(z * 256 + b) * 3 + 1];
        float bz = xyz[(z * 256 + b) * 3 + 2];
        #pragma unroll
        for (int hf = 0; hf < 2; ++hf) {
            __syncthreads();   // previous-phase readers of hid/bas are done
            if (t < 128) {
                int a = hf * 128 + t;
                float dx = xyz[(z * 256 + a) * 3 + 0] - bx;
                float dy = xyz[(z * 256 + a) * 3 + 1] - by;
                float dz = xyz[(z * 256 + a) * 3 + 2] - bz;
                float r = sqrtf(dx * dx + dy * dy + dz * dz + 1e-12f);
                float r5 = r - 5.f, r10 = r - 10.f;
                bas[0][t] = expf(-GAMMA * r * r);
                bas[1][t] = expf(-GAMMA * r5 * r5);
                bas[2][t] = expf(-GAMMA * r10 * r10);
            }
            __syncthreads();
            for (int e = t; e < 12800; e += 256) {
                int h = e >> 7, a = e & 127;
                float pre = bas[0][a] * rw1s[h] + bas[1][a] * rw1s[100 + h] + bas[2][a] * rw1s[200 + h];
                hid[h * 128 + a] = pre / (1.f + expf(-pre));   // swish
            }
            __syncthreads();
            const float4* wg = (const float4*)(W + (size_t)(z * 256 + b) * 3200);
            const float4* hl = (const float4*)hid;
            #pragma unroll 4
            for (int h = 0; h < 100; ++h) {
                float4 hv = hl[h * 32 + a_grp];
                float4 wv = wg[h * 8 + i_grp];
                acc[hf][0][0] += hv.x * wv.x; acc[hf][0][1] += hv.x * wv.y;
                acc[hf][0][2] += hv.x * wv.z; acc[hf][0][3] += hv.x * wv.w;
                acc[hf][1][0] += hv.y * wv.x; acc[hf][1][1] += hv.y * wv.y;
                acc[hf][1][2] += hv.y * wv.z; acc[hf][1][3] += hv.y * wv.w;
                acc[hf][2][0] += hv.z * wv.x; acc[hf][2][1] += hv.z * wv.y;
                acc[hf][2][2] += hv.z * wv.z; acc[hf][2][3] += hv.z * wv.w;
                acc[hf][3][0] += hv.w * wv.x; acc[hf][3][1] += hv.w * wv.y;
                acc[hf][3][2] += hv.w * wv.z; acc[hf][3][3] += hv.w * wv.w;
            }
        }
    }

    size_t base = (size_t)(z * 64 + bc) * 256 * 32;
    #pragma unroll
    for (int hf = 0; hf < 2; ++hf)
        #pragma unroll
        for (int ai = 0; ai < 4; ++ai) {
            int a = hf * 128 + a_grp * 4 + ai;
            float4 v = make_float4(acc[hf][ai][0], acc[hf][ai][1], acc[hf][ai][2], acc[hf][ai][3]);
            ((float4*)part)[(base + (size_t)a * 32) / 4 + i_grp] = v;
        }
}

// ---------------------------------------------------------------------------
// K3: reduce partials over bc, abs+mask+scale, pool over a, normalize,
//     fc3 + leaky_relu + fc2. One block per z.
// ---------------------------------------------------------------------------
__global__ __launch_bounds__(256) void k3_final(const float* __restrict__ part,
                                                const int* __restrict__ mask,
                                                const float* __restrict__ fc3_w,
                                                const float* __restrict__ fc3_b,
                                                const float* __restrict__ fc2_w,
                                                const float* __restrict__ fc2_b,
                                                float* __restrict__ out) {
    int z = blockIdx.x;
    int t = threadIdx.x;   // = a
    __shared__ float red[256 * 33];

    float4 s[8];
    #pragma unroll
    for (int q = 0; q < 8; ++q) s[q] = make_float4(0.f, 0.f, 0.f, 0.f);
    for (int bc = 0; bc < 64; ++bc) {
        const float4* p4 = (const float4*)(part + ((size_t)(z * 64 + bc) * 256 + t) * 32);
        #pragma unroll
        for (int q = 0; q < 8; ++q) {
            float4 v = p4[q];
            s[q].x += v.x; s[q].y += v.y; s[q].z += v.z; s[q].w += v.w;
        }
    }
    float sc = (mask[z * 256 + t] != 0) ? 0.0625f : 0.f;  // /sqrt(256), after abs
    #pragma unroll
    for (int q = 0; q < 8; ++q) {
        red[t * 33 + q * 4 + 0] = fabsf(s[q].x) * sc;
        red[t * 33 + q * 4 + 1] = fabsf(s[q].y) * sc;
        red[t * 33 + q * 4 + 2] = fabsf(s[q].z) * sc;
        red[t * 33 + q * 4 + 3] = fabsf(s[q].w) * sc;
    }
    __syncthreads();
    for (int stp = 128; stp > 0; stp >>= 1) {
        if (t < stp) {
            #pragma unroll
            for (int i = 0; i < 32; ++i) red[t * 33 + i] += red[(t + stp) * 33 + i];
        }
        __syncthreads();
    }
    // pooled[i] now at red[i]
    if (t < 32) {
        float v = red[t];
        float sm = v;
        #pragma unroll
        for (int off = 16; off; off >>= 1) sm += __shfl_xor(sm, off, 64);
        float mean = sm / 32.f;
        float d = v - mean;
        float ss = d * d;
        #pragma unroll
        for (int off = 16; off; off >>= 1) ss += __shfl_xor(ss, off, 64);
        float stdv = sqrtf(ss / 31.f);    // ddof=1
        red[t] = d / (stdv + 1e-6f);
    }
    __syncthreads();
    if (t < 32) {
        float h1 = fc3_b[t];
        #pragma unroll
        for (int i = 0; i < 32; ++i) h1 += red[i] * fc3_w[i * 32 + t];
        h1 = (h1 >= 0.f) ? h1 : 0.01f * h1;
        float yterm = h1 * fc2_w[t];
        #pragma unroll
        for (int off = 16; off; off >>= 1) yterm += __shfl_xor(yterm, off, 64);
        if (t == 0) out[z] = yterm + fc2_b[0];
    }
}

extern "C" void kernel_launch(void* const* d_in, const int* in_sizes, int n_in,
                              void* d_out, int out_size, void* d_ws, size_t ws_size,
                              hipStream_t stream) {
    const float* x    = (const float*)d_in[0];
    const float* xyz  = (const float*)d_in[1];
    const int*   mask = (const int*)d_in[2];
    const float* rw1  = (const float*)d_in[3];
    const float* rw2  = (const float*)d_in[4];
    const float* fc3w = (const float*)d_in[5];
    const float* fc3b = (const float*)d_in[6];
    const float* fc2w = (const float*)d_in[7];
    const float* fc2b = (const float*)d_in[8];
    float* out = (float*)d_out;

    float* W    = (float*)d_ws;                                     // 4*256*100*32 f32 = 13.1 MB
    float* part = (float*)((char*)d_ws + (size_t)4 * 256 * 100 * 32 * 4);  // 4*64*256*32 f32 = 8.4 MB

    hipLaunchKernelGGL(k1_W,     dim3(256), dim3(256), 0, stream, x, rw2, W);
    hipLaunchKernelGGL(k2_main,  dim3(256), dim3(256), 0, stream, xyz, rw1, W, part);
    hipLaunchKernelGGL(k3_final, dim3(4),   dim3(256), 0, stream, part, mask, fc3w, fc3b, fc2w, fc2b, out);
}

// Round 3
// 89.232 us; speedup vs baseline: 1.8271x; 1.8271x over previous
//
#include <hip/hip_runtime.h>
#include <math.h>

// Problem constants
#define NZ 4
#define NN 256
#define NC 32
#define NH 100
#define GAMMA 0.3f   // 1/spacing = NUM_BASIS/MAX_RADIUS = 3/10

// ---------------------------------------------------------------------------
// K1: W[z,b,h,i] = sum_j rw2[h, i*32+j] * x[z,b,j]
// grid: 256 blocks = z(4) x bgrp(64), 4 b's per block; 256 threads
// ---------------------------------------------------------------------------
__global__ __launch_bounds__(256) void k1_W(const float* __restrict__ x,
                                            const float* __restrict__ rw2,
                                            float* __restrict__ W) {
    int bid = blockIdx.x;
    int z = bid >> 6, bgrp = bid & 63;
    int b0 = bgrp * 4;
    int t = threadIdx.x;
    __shared__ float xs[4][32];
    if (t < 128) {
        int q = t >> 5, j = t & 31;
        xs[q][j] = x[(z * 256 + b0 + q) * 32 + j];
    }
    __syncthreads();
    for (int e = t; e < 3200; e += 256) {
        int h = e >> 5, i = e & 31;
        const float4* w4 = (const float4*)(rw2 + h * 1024 + i * 32);
        float a0 = 0.f, a1 = 0.f, a2 = 0.f, a3 = 0.f;
        #pragma unroll
        for (int j4 = 0; j4 < 8; ++j4) {
            float4 wv = w4[j4];
            int j = j4 * 4;
            a0 += wv.x * xs[0][j] + wv.y * xs[0][j + 1] + wv.z * xs[0][j + 2] + wv.w * xs[0][j + 3];
            a1 += wv.x * xs[1][j] + wv.y * xs[1][j + 1] + wv.z * xs[1][j + 2] + wv.w * xs[1][j + 3];
            a2 += wv.x * xs[2][j] + wv.y * xs[2][j + 1] + wv.z * xs[2][j + 2] + wv.w * xs[2][j + 3];
            a3 += wv.x * xs[3][j] + wv.y * xs[3][j + 1] + wv.z * xs[3][j + 2] + wv.w * xs[3][j + 3];
        }
        W[((z * 256 + b0 + 0) * 100 + h) * 32 + i] = a0;
        W[((z * 256 + b0 + 1) * 100 + h) * 32 + i] = a1;
        W[((z * 256 + b0 + 2) * 100 + h) * 32 + i] = a2;
        W[((z * 256 + b0 + 3) * 100 + h) * 32 + i] = a3;
    }
}

// ---------------------------------------------------------------------------
// K2: part[z,bc,a,i] += sum_{b in chunk of 4} sum_h hid(z,a,b,h) * W[z,b,h,i]
// grid: 1024 blocks = z(4) x bc(64) x ah(4); each block: 64 a's, 4 b's.
// 256 threads, tile 2a x 4i. LDS ~27 KB -> 4 blocks/CU co-resident.
// ---------------------------------------------------------------------------
__global__ __launch_bounds__(256) void k2_main(const float* __restrict__ xyz,
                                               const float* __restrict__ rw1,
                                               const float* __restrict__ W,
                                               float* __restrict__ part) {
    int bid = blockIdx.x;
    int z = bid >> 8;
    int r = bid & 255;
    int bc = r >> 2, ah = r & 3;
    int b0 = bc * 4, a0 = ah * 64;
    int t = threadIdx.x;
    int i_grp = t & 7;    // 0..7  (4 i's each, float4)
    int a_grp = t >> 3;   // 0..31 (2 a's each)

    __shared__ __align__(16) float hid[100][64];
    __shared__ float bas[3][64];
    __shared__ float rw1s[304];
    for (int e = t; e < 300; e += 256) rw1s[e] = rw1[e];

    float acc[2][4];
    #pragma unroll
    for (int u = 0; u < 2; ++u)
        #pragma unroll
        for (int v = 0; v < 4; ++v) acc[u][v] = 0.f;

    for (int bi = 0; bi < 4; ++bi) {
        int b = b0 + bi;
        float bx = xyz[(z * 256 + b) * 3 + 0];
        float by = xyz[(z * 256 + b) * 3 + 1];
        float bz = xyz[(z * 256 + b) * 3 + 2];
        __syncthreads();   // previous-phase readers of hid/bas done (and rw1s ready on iter 0)
        if (t < 192) {
            int k = t >> 6, a = t & 63;
            int ga = (z * 256 + a0 + a) * 3;
            float dx = xyz[ga + 0] - bx;
            float dy = xyz[ga + 1] - by;
            float dz = xyz[ga + 2] - bz;
            float rr = sqrtf(dx * dx + dy * dy + dz * dz + 1e-12f);
            float c = rr - 5.f * (float)k;
            bas[k][a] = __expf(-GAMMA * c * c);
        }
        __syncthreads();
        for (int e = t; e < 6400; e += 256) {
            int h = e >> 6, a = e & 63;
            float pre = bas[0][a] * rw1s[h] + bas[1][a] * rw1s[100 + h] + bas[2][a] * rw1s[200 + h];
            hid[h][a] = pre * __builtin_amdgcn_rcpf(1.f + __expf(-pre));   // swish
        }
        __syncthreads();
        const float4* wg = (const float4*)(W + (size_t)(z * 256 + b) * 3200);
        #pragma unroll 4
        for (int h = 0; h < 100; ++h) {
            float2 hv = *(const float2*)&hid[h][a_grp * 2];
            float4 wv = wg[h * 8 + i_grp];
            acc[0][0] += hv.x * wv.x; acc[0][1] += hv.x * wv.y;
            acc[0][2] += hv.x * wv.z; acc[0][3] += hv.x * wv.w;
            acc[1][0] += hv.y * wv.x; acc[1][1] += hv.y * wv.y;
            acc[1][2] += hv.y * wv.z; acc[1][3] += hv.y * wv.w;
        }
    }

    int a = a0 + a_grp * 2;
    size_t base = ((size_t)((z * 64 + bc) * 256) + a) * 32 + i_grp * 4;
    *(float4*)&part[base]      = make_float4(acc[0][0], acc[0][1], acc[0][2], acc[0][3]);
    *(float4*)&part[base + 32] = make_float4(acc[1][0], acc[1][1], acc[1][2], acc[1][3]);
}

// ---------------------------------------------------------------------------
// K3a: reduce partials over bc(64), abs+mask+scale, partial pool over 16 a's.
// grid: 64 blocks = z(4) x ag(16); 256 threads (a_loc 16 x i-pair 16)
// ---------------------------------------------------------------------------
__global__ __launch_bounds__(256) void k3a_reduce(const float* __restrict__ part,
                                                  const int* __restrict__ mask,
                                                  float* __restrict__ pooled_part) {
    int blk = blockIdx.x;
    int z = blk >> 4, ag = blk & 15;
    int t = threadIdx.x;
    int a_loc = t >> 4, ih = t & 15;
    int a = ag * 16 + a_loc;
    float sx = 0.f, sy = 0.f;
    const float* base = part + ((size_t)(z * 64) * 256 + a) * 32 + ih * 2;
    for (int bcc = 0; bcc < 64; ++bcc) {
        float2 v = *(const float2*)(base + (size_t)bcc * 256 * 32);
        sx += v.x; sy += v.y;
    }
    float sc = (mask[z * 256 + a] != 0) ? 0.0625f : 0.f;  // 1/sqrt(256)
    __shared__ float pool[16][32];
    pool[a_loc][ih * 2 + 0] = fabsf(sx) * sc;
    pool[a_loc][ih * 2 + 1] = fabsf(sy) * sc;
    __syncthreads();
    if (t < 32) {
        float v = 0.f;
        #pragma unroll
        for (int rr = 0; rr < 16; ++rr) v += pool[rr][t];
        pooled_part[(z * 16 + ag) * 32 + t] = v;
    }
}

// ---------------------------------------------------------------------------
// K3b: final pool over ag(16), normalize (ddof=1), fc3+leaky, fc2 -> out[4]
// 1 block, 128 threads (z = t>>5, i = t&31)
// ---------------------------------------------------------------------------
__global__ __launch_bounds__(128) void k3b_final(const float* __restrict__ pooled_part,
                                                 const float* __restrict__ fc3_w,
                                                 const float* __restrict__ fc3_b,
                                                 const float* __restrict__ fc2_w,
                                                 const float* __restrict__ fc2_b,
                                                 float* __restrict__ out) {
    int t = threadIdx.x;
    int z = t >> 5, i = t & 31;
    float s = 0.f;
    #pragma unroll
    for (int ag = 0; ag < 16; ++ag) s += pooled_part[(z * 16 + ag) * 32 + i];
    float sm = s;
    #pragma unroll
    for (int off = 16; off; off >>= 1) sm += __shfl_xor(sm, off, 32);
    float mean = sm * (1.f / 32.f);
    float d = s - mean;
    float ss = d * d;
    #pragma unroll
    for (int off = 16; off; off >>= 1) ss += __shfl_xor(ss, off, 32);
    float stdv = sqrtf(ss * (1.f / 31.f));   // ddof=1
    float nv = d / (stdv + 1e-6f);
    __shared__ float pn[4][32];
    pn[z][i] = nv;
    __syncthreads();
    float h1 = fc3_b[i];
    #pragma unroll
    for (int j = 0; j < 32; ++j) h1 += pn[z][j] * fc3_w[j * 32 + i];
    h1 = (h1 >= 0.f) ? h1 : 0.01f * h1;
    float y = h1 * fc2_w[i];
    #pragma unroll
    for (int off = 16; off; off >>= 1) y += __shfl_xor(y, off, 32);
    if (i == 0) out[z] = y + fc2_b[0];
}

extern "C" void kernel_launch(void* const* d_in, const int* in_sizes, int n_in,
                              void* d_out, int out_size, void* d_ws, size_t ws_size,
                              hipStream_t stream) {
    const float* x    = (const float*)d_in[0];
    const float* xyz  = (const float*)d_in[1];
    const int*   mask = (const int*)d_in[2];
    const float* rw1  = (const float*)d_in[3];
    const float* rw2  = (const float*)d_in[4];
    const float* fc3w = (const float*)d_in[5];
    const float* fc3b = (const float*)d_in[6];
    const float* fc2w = (const float*)d_in[7];
    const float* fc2b = (const float*)d_in[8];
    float* out = (float*)d_out;

    float* W    = (float*)d_ws;                                      // 13,107,200 B
    float* part = (float*)((char*)d_ws + 13107200);                  //  8,388,608 B
    float* pooled_part = (float*)((char*)d_ws + 13107200 + 8388608); //      8,192 B

    hipLaunchKernelGGL(k1_W,       dim3(256),  dim3(256), 0, stream, x, rw2, W);
    hipLaunchKernelGGL(k2_main,    dim3(1024), dim3(256), 0, stream, xyz, rw1, W, part);
    hipLaunchKernelGGL(k3a_reduce, dim3(64),   dim3(256), 0, stream, part, mask, pooled_part);
    hipLaunchKernelGGL(k3b_final,  dim3(1),    dim3(128), 0, stream, pooled_part, fc3w, fc3b, fc2w, fc2b, out);
}